// Round 1
// baseline (550.603 us; speedup 1.0000x reference)
//
#include <hip/hip_runtime.h>
#include <stdint.h>

typedef __bf16 bf16x8 __attribute__((ext_vector_type(8)));
typedef float  floatx4 __attribute__((ext_vector_type(4)));

__device__ __forceinline__ unsigned short f2b(float x){
    unsigned u = __float_as_uint(x);
    u = u + 0x7FFFu + ((u >> 16) & 1u);          // RNE
    return (unsigned short)(u >> 16);
}
__device__ __forceinline__ float b2f(unsigned short h){
    return __uint_as_float(((unsigned)h) << 16);
}

// ---------------- degree / CSR build ----------------

__global__ __launch_bounds__(256) void k_count(const int* __restrict__ dst,
                                               int* __restrict__ cnt, int E_){
    int e = blockIdx.x * 256 + threadIdx.x;
    if (e < E_) atomicAdd(&cnt[dst[e]], 1);
}

__global__ __launch_bounds__(256) void k_dinv(const int* __restrict__ cnt,
                                              float* __restrict__ dinv, int n){
    int i = blockIdx.x * 256 + threadIdx.x;
    if (i < n) dinv[i] = rsqrtf((float)cnt[i] + 1.0f);
}

// block sums over 1024 ints each (cnt padded with zeros to NB*1024)
__global__ __launch_bounds__(256) void k_blocksum(const int* __restrict__ cnt,
                                                  int* __restrict__ part){
    int t = threadIdx.x;
    const int4* p = (const int4*)(cnt + (size_t)blockIdx.x * 1024);
    int4 v = p[t];
    int s = v.x + v.y + v.z + v.w;
    #pragma unroll
    for (int o = 32; o > 0; o >>= 1) s += __shfl_down(s, o);
    __shared__ int wsum[4];
    if ((t & 63) == 0) wsum[t >> 6] = s;
    __syncthreads();
    if (t == 0) part[blockIdx.x] = wsum[0] + wsum[1] + wsum[2] + wsum[3];
}

// exclusive scan of 128 partials in-place (NB <= 128; tail is zero)
__global__ __launch_bounds__(128) void k_scanpart(int* __restrict__ part){
    __shared__ int s[128];
    int t = threadIdx.x;
    s[t] = part[t];
    __syncthreads();
    for (int o = 1; o < 128; o <<= 1){
        int v = (t >= o) ? s[t - o] : 0;
        __syncthreads();
        s[t] += v;
        __syncthreads();
    }
    part[t] = (t == 0) ? 0 : s[t - 1];
}

__global__ __launch_bounds__(256) void k_offsets(const int* __restrict__ cnt,
                                                 const int* __restrict__ part,
                                                 int* __restrict__ off){
    int b = blockIdx.x, t = threadIdx.x;
    const int4* p = (const int4*)(cnt + (size_t)b * 1024);
    int4 v = p[t];
    int s = v.x + v.y + v.z + v.w;
    __shared__ int sd[256];
    sd[t] = s;
    __syncthreads();
    for (int o = 1; o < 256; o <<= 1){
        int vv = (t >= o) ? sd[t - o] : 0;
        __syncthreads();
        sd[t] += vv;
        __syncthreads();
    }
    int base = part[b] + (t ? sd[t - 1] : 0);
    int4 w;
    w.x = base;
    w.y = base + v.x;
    w.z = base + v.x + v.y;
    w.w = base + v.x + v.y + v.z;
    ((int4*)(off + (size_t)b * 1024))[t] = w;
}

__global__ __launch_bounds__(256) void k_bucket(const int* __restrict__ src,
                                                const int* __restrict__ dst,
                                                const int* __restrict__ off,
                                                int* __restrict__ cur,
                                                int* __restrict__ csr, int E_){
    int e = blockIdx.x * 256 + threadIdx.x;
    if (e >= E_) return;
    int d = dst[e];
    int pos = off[d] + atomicAdd(&cur[d], 1);
    csr[pos] = src[e];
}

// ---------------- weight reorder to MFMA B-fragment order ----------------
// frag layout for mfma_f32_16x16x32_bf16 B: lane l holds B[k=(l>>4)*8+j][n=(l&15)]
// stored frag-major: base = ((ct*4+kc)*64 + lane)*8
__global__ __launch_bounds__(256) void k_wconv(const float* __restrict__ W1,
                                               const float* __restrict__ W2,
                                               unsigned short* __restrict__ wf1,
                                               unsigned short* __restrict__ wf2){
    int f = blockIdx.x * 256 + threadIdx.x;
    if (f >= 3072) return;
    const float* W; unsigned short* o; int ncol, lf;
    if (f < 2048){ W = W1; o = wf1; ncol = 128; lf = f; }
    else         { W = W2; o = wf2; ncol = 64;  lf = f - 2048; }
    int lane = lf & 63;
    int ctkc = lf >> 6;
    int kc = ctkc & 3, ct = ctkc >> 2;
    int col = ct * 16 + (lane & 15);
    int k0  = kc * 32 + (lane >> 4) * 8;
    unsigned short* d = o + (size_t)lf * 8;
    #pragma unroll
    for (int j = 0; j < 8; j++) d[j] = f2b(W[(k0 + j) * ncol + col]);
}

// ---------------- GEMM1: hs1 = bf16( (x @ W1) * dinv[row] ) ----------------
__global__ __launch_bounds__(256) void k_gemm1(const float* __restrict__ x,
                                               const unsigned short* __restrict__ wf,
                                               const float* __restrict__ dinv,
                                               unsigned short* __restrict__ hs, int n){
    __shared__ unsigned short Wl[16384];      // 32KB, fragment-order
    __shared__ unsigned short Al[64 * 136];   // padded rows: 272B stride
    int t = threadIdx.x;
    long rowBase = (long)blockIdx.x * 64;
    {   // copy W fragments (plain linear copy)
        const uint4* s4 = (const uint4*)wf;
        uint4* d4 = (uint4*)Wl;
        #pragma unroll
        for (int i = 0; i < 8; i++) d4[t + i * 256] = s4[t + i * 256];
    }
    {   // stage A tile fp32 -> bf16 (tile is contiguous in memory)
        const float4* xs = (const float4*)(x + rowBase * 128);
        #pragma unroll
        for (int k = 0; k < 8; k++){
            int i = t + k * 256;
            int r = i >> 5, c4 = (i & 31) << 2;
            float4 v = make_float4(0.f, 0.f, 0.f, 0.f);
            if (rowBase + r < n) v = xs[i];
            unsigned lo = (unsigned)f2b(v.x) | ((unsigned)f2b(v.y) << 16);
            unsigned hi = (unsigned)f2b(v.z) | ((unsigned)f2b(v.w) << 16);
            *(uint2*)&Al[r * 136 + c4] = make_uint2(lo, hi);
        }
    }
    __syncthreads();
    int w = t >> 6, lane = t & 63, lr = lane & 15, q = lane >> 4;
    floatx4 zero = {0.f, 0.f, 0.f, 0.f};
    floatx4 acc[8];
    #pragma unroll
    for (int ct = 0; ct < 8; ct++) acc[ct] = zero;
    #pragma unroll
    for (int kc = 0; kc < 4; kc++){
        bf16x8 af = *(const bf16x8*)&Al[(w * 16 + lr) * 136 + kc * 32 + q * 8];
        #pragma unroll
        for (int ct = 0; ct < 8; ct++){
            bf16x8 bf = *(const bf16x8*)&Wl[((ct * 4 + kc) * 64 + lane) * 8];
            acc[ct] = __builtin_amdgcn_mfma_f32_16x16x32_bf16(af, bf, acc[ct], 0, 0, 0);
        }
    }
    long r0 = rowBase + w * 16 + q * 4;
    #pragma unroll
    for (int r = 0; r < 4; r++){
        long row = r0 + r;
        if (row >= n) continue;
        float dv = dinv[row];
        unsigned short* orow = hs + row * 128 + lr;
        #pragma unroll
        for (int ct = 0; ct < 8; ct++) orow[ct * 16] = f2b(acc[ct][r] * dv);
    }
}

// ---------------- GEMM2: hs2 = bf16( (z1 @ W2) * dinv[row] ) ----------------
__global__ __launch_bounds__(256) void k_gemm2(const unsigned short* __restrict__ z1,
                                               const unsigned short* __restrict__ wf,
                                               const float* __restrict__ dinv,
                                               unsigned short* __restrict__ hs, int n){
    __shared__ unsigned short Wl[8192];       // 16KB
    __shared__ unsigned short Al[64 * 136];
    int t = threadIdx.x;
    long rowBase = (long)blockIdx.x * 64;
    {
        const uint4* s4 = (const uint4*)wf;
        uint4* d4 = (uint4*)Wl;
        #pragma unroll
        for (int i = 0; i < 4; i++) d4[t + i * 256] = s4[t + i * 256];
    }
    {
        const uint4* zs = (const uint4*)(z1 + rowBase * 128);
        #pragma unroll
        for (int k = 0; k < 4; k++){
            int i = t + k * 256;
            int r = i >> 4, c8 = (i & 15) << 3;
            uint4 v = make_uint4(0u, 0u, 0u, 0u);
            if (rowBase + r < n) v = zs[i];
            *(uint4*)&Al[r * 136 + c8] = v;
        }
    }
    __syncthreads();
    int w = t >> 6, lane = t & 63, lr = lane & 15, q = lane >> 4;
    floatx4 zero = {0.f, 0.f, 0.f, 0.f};
    floatx4 acc[4];
    #pragma unroll
    for (int ct = 0; ct < 4; ct++) acc[ct] = zero;
    #pragma unroll
    for (int kc = 0; kc < 4; kc++){
        bf16x8 af = *(const bf16x8*)&Al[(w * 16 + lr) * 136 + kc * 32 + q * 8];
        #pragma unroll
        for (int ct = 0; ct < 4; ct++){
            bf16x8 bf = *(const bf16x8*)&Wl[((ct * 4 + kc) * 64 + lane) * 8];
            acc[ct] = __builtin_amdgcn_mfma_f32_16x16x32_bf16(af, bf, acc[ct], 0, 0, 0);
        }
    }
    long r0 = rowBase + w * 16 + q * 4;
    #pragma unroll
    for (int r = 0; r < 4; r++){
        long row = r0 + r;
        if (row >= n) continue;
        float dv = dinv[row];
        unsigned short* orow = hs + row * 64 + lr;
        #pragma unroll
        for (int ct = 0; ct < 4; ct++) orow[ct * 16] = f2b(acc[ct][r] * dv);
    }
}

// ---------------- aggregation layer 1 (128 cols, wave per node) ----------------
// z1[i] = bf16( relu( dinv[i]*(sum_{in(i)} hs1[src] + hs1[i]) + b1 ) )
__global__ __launch_bounds__(256) void k_agg1(const unsigned short* __restrict__ hs,
                                              const int* __restrict__ off,
                                              const int* __restrict__ cnt,
                                              const int* __restrict__ csr,
                                              const float* __restrict__ dinv,
                                              const float* __restrict__ b,
                                              unsigned short* __restrict__ z, int n){
    int wid = (blockIdx.x * 256 + threadIdx.x) >> 6;
    int lane = threadIdx.x & 63;
    if (wid >= n) return;
    size_t i = (size_t)wid;
    int start = off[wid], c = cnt[wid];
    unsigned v0 = *(const unsigned*)(hs + i * 128 + lane * 2);
    float a0 = b2f((unsigned short)v0);
    float a1 = b2f((unsigned short)(v0 >> 16));
    for (int base = 0; base < c; base += 64){
        int m = c - base; if (m > 64) m = 64;
        int sl = (base + lane < c) ? csr[start + base + lane] : 0;
        for (int j = 0; j < m; j++){
            size_t s = (size_t)__shfl(sl, j);
            unsigned v = *(const unsigned*)(hs + s * 128 + lane * 2);
            a0 += b2f((unsigned short)v);
            a1 += b2f((unsigned short)(v >> 16));
        }
    }
    float dv = dinv[wid];
    float2 bb = ((const float2*)b)[lane];
    float z0 = fmaxf(fmaf(dv, a0, bb.x), 0.f);
    float z1 = fmaxf(fmaf(dv, a1, bb.y), 0.f);
    *(unsigned*)(z + i * 128 + lane * 2) = (unsigned)f2b(z0) | ((unsigned)f2b(z1) << 16);
}

// ---------------- aggregation layer 2 (64 cols, wave per node, fp32 out) -------
__global__ __launch_bounds__(256) void k_agg2(const unsigned short* __restrict__ hs,
                                              const int* __restrict__ off,
                                              const int* __restrict__ cnt,
                                              const int* __restrict__ csr,
                                              const float* __restrict__ dinv,
                                              const float* __restrict__ b,
                                              float* __restrict__ z, int n){
    int wid = (blockIdx.x * 256 + threadIdx.x) >> 6;
    int lane = threadIdx.x & 63;
    if (wid >= n) return;
    size_t i = (size_t)wid;
    int start = off[wid], c = cnt[wid];
    float a = b2f(hs[i * 64 + lane]);
    for (int base = 0; base < c; base += 64){
        int m = c - base; if (m > 64) m = 64;
        int sl = (base + lane < c) ? csr[start + base + lane] : 0;
        for (int j = 0; j < m; j++){
            size_t s = (size_t)__shfl(sl, j);
            a += b2f(hs[s * 64 + lane]);
        }
    }
    z[i * 64 + lane] = fmaf(dinv[wid], a, b[lane]);
}

// ---------------- decode: out[e] = dot(z2[s], z2[t]) over 64 dims --------------
__global__ __launch_bounds__(256) void k_decode(const float* __restrict__ z,
                                                const int* __restrict__ es,
                                                const int* __restrict__ et,
                                                float* __restrict__ out, int m){
    int wid = (blockIdx.x * 256 + threadIdx.x) >> 6;
    int lane = threadIdx.x & 63;
    if (wid >= m) return;
    size_t s = (size_t)es[wid], t2 = (size_t)et[wid];
    float p = z[s * 64 + lane] * z[t2 * 64 + lane];
    #pragma unroll
    for (int o = 32; o > 0; o >>= 1) p += __shfl_xor(p, o);
    if (lane == 0) out[wid] = p;
}

// ---------------- launcher ----------------

extern "C" void kernel_launch(void* const* d_in, const int* in_sizes, int n_in,
                              void* d_out, int out_size, void* d_ws, size_t ws_size,
                              hipStream_t stream){
    const float* x   = (const float*)d_in[0];
    const int*   ei  = (const int*)d_in[1];
    const int*   eli = (const int*)d_in[2];
    const float* W1  = (const float*)d_in[3];
    const float* b1  = (const float*)d_in[4];
    const float* W2  = (const float*)d_in[5];
    const float* b2  = (const float*)d_in[6];
    float* out = (float*)d_out;

    int N_  = in_sizes[0] / 128;
    int E_  = in_sizes[1] / 2;
    int EL_ = in_sizes[2] / 2;
    int NB  = (N_ + 1023) / 1024;     // scan blocks (<=128 required; 98 here)
    size_t NP = (size_t)NB * 1024;

    char* w = (char*)d_ws;
    size_t o = 0;
    auto alloc = [&](size_t bytes) -> size_t {
        size_t r = o; o += (bytes + 511) & ~(size_t)511; return r;
    };
    size_t o_cnt  = alloc(NP * 4);
    size_t o_cur  = alloc(NP * 4);
    size_t o_part = alloc(512);
    size_t zbytes = o;                 // zero cnt + cur + part each call
    size_t o_dinv = alloc((size_t)N_ * 4);
    size_t o_off  = alloc(NP * 4);
    size_t o_csr  = alloc((size_t)E_ * 4);
    size_t o_wf1  = alloc(16384 * 2);
    size_t o_wf2  = alloc(8192 * 2);
    size_t o_hs1  = alloc((size_t)N_ * 128 * 2);
    size_t o_z1   = alloc((size_t)N_ * 128 * 2);

    int* cnt  = (int*)(w + o_cnt);
    int* cur  = (int*)(w + o_cur);
    int* part = (int*)(w + o_part);
    float* dinv = (float*)(w + o_dinv);
    int* off  = (int*)(w + o_off);
    int* csr  = (int*)(w + o_csr);
    unsigned short* wf1 = (unsigned short*)(w + o_wf1);
    unsigned short* wf2 = (unsigned short*)(w + o_wf2);
    unsigned short* hs1 = (unsigned short*)(w + o_hs1);
    unsigned short* z1  = (unsigned short*)(w + o_z1);
    unsigned short* hs2 = hs1;                 // hs1 dead after agg1
    float* z2 = (float*)(w + o_z1);            // z1 dead after gemm2 (N*64*4 == N*128*2)

    hipMemsetAsync(w, 0, zbytes, stream);
    k_count   <<<(E_ + 255) / 256, 256, 0, stream>>>(ei + E_, cnt, E_);
    k_dinv    <<<(N_ + 255) / 256, 256, 0, stream>>>(cnt, dinv, N_);
    k_blocksum<<<NB, 256, 0, stream>>>(cnt, part);
    k_scanpart<<<1, 128, 0, stream>>>(part);
    k_offsets <<<NB, 256, 0, stream>>>(cnt, part, off);
    k_bucket  <<<(E_ + 255) / 256, 256, 0, stream>>>(ei, ei + E_, off, cur, csr, E_);
    k_wconv   <<<12, 256, 0, stream>>>(W1, W2, wf1, wf2);
    k_gemm1   <<<(N_ + 63) / 64, 256, 0, stream>>>(x, wf1, dinv, hs1, N_);
    k_agg1    <<<(N_ + 3) / 4, 256, 0, stream>>>(hs1, off, cnt, csr, dinv, b1, z1, N_);
    k_gemm2   <<<(N_ + 63) / 64, 256, 0, stream>>>(z1, wf2, dinv, hs2, N_);
    k_agg2    <<<(N_ + 3) / 4, 256, 0, stream>>>(hs2, off, cnt, csr, dinv, b2, z2, N_);
    k_decode  <<<(EL_ + 3) / 4, 256, 0, stream>>>(z2, eli, eli + EL_, out, EL_);
}

// Round 3
// 415.858 us; speedup vs baseline: 1.3240x; 1.3240x over previous
//
#include <hip/hip_runtime.h>
#include <stdint.h>

typedef __bf16 bf16x8 __attribute__((ext_vector_type(8)));
typedef float  floatx4 __attribute__((ext_vector_type(4)));

__device__ __forceinline__ unsigned short f2b(float x){
    unsigned u = __float_as_uint(x);
    u = u + 0x7FFFu + ((u >> 16) & 1u);          // RNE
    return (unsigned short)(u >> 16);
}
__device__ __forceinline__ float b2f(unsigned short h){
    return __uint_as_float(((unsigned)h) << 16);
}

// ================= CSR build: two-level counting sort (no global atomics) ====
// bin = dst >> 7 (128 nodes per bin). EPB = 8192 edges per hist/scatter block.

__global__ __launch_bounds__(256) void k_hist(const int* __restrict__ dst,
                                              int* __restrict__ hist,
                                              int E_, int nbins, int nblk){
    __shared__ int h[1024];
    int t = threadIdx.x, blk = blockIdx.x;
    for (int i = t; i < nbins; i += 256) h[i] = 0;
    __syncthreads();
    int base = blk * 8192;
    #pragma unroll 4
    for (int j = 0; j < 32; j++){
        int e = base + j * 256 + t;
        if (e < E_) atomicAdd(&h[dst[e] >> 7], 1);
    }
    __syncthreads();
    for (int i = t; i < nbins; i += 256) hist[(size_t)i * nblk + blk] = h[i];
}

// per-bin exclusive scan across blocks, in place; bin totals out. 1 wave/bin.
__global__ __launch_bounds__(64) void k_binscanA(int* __restrict__ hist,
                                                 int* __restrict__ btot, int nblk){
    int bin = blockIdx.x, lane = threadIdx.x;
    int carry = 0;
    for (int base = 0; base < nblk; base += 64){
        int idx = bin * nblk + base + lane;
        bool inb = (base + lane) < nblk;
        int v = inb ? hist[idx] : 0;
        int orig = v;
        #pragma unroll
        for (int o = 1; o < 64; o <<= 1){
            int u = __shfl_up(v, o);
            if (lane >= o) v += u;
        }
        if (inb) hist[idx] = v - orig + carry;
        carry += __shfl(v, 63);
    }
    if (lane == 0) btot[bin] = carry;
}

// scan of bin totals -> binoff[0..nbins]  (requires nbins <= 1024)
__global__ __launch_bounds__(1024) void k_binscanB(const int* __restrict__ btot,
                                                   int* __restrict__ boff, int nbins){
    __shared__ int s[1024];
    int t = threadIdx.x;
    s[t] = (t < nbins) ? btot[t] : 0;
    __syncthreads();
    for (int o = 1; o < 1024; o <<= 1){
        int v = (t >= o) ? s[t - o] : 0;
        __syncthreads();
        s[t] += v;
        __syncthreads();
    }
    if (t == 0) boff[0] = 0;
    if (t < nbins) boff[t + 1] = s[t];
}

// partition edges into bin segments; positions via LDS counters only.
// packed word (UNSIGNED): (dst & 127) << 25 | src     (needs N < 2^25)
__global__ __launch_bounds__(256) void k_scatter(const int* __restrict__ src,
                                                 const int* __restrict__ dst,
                                                 const int* __restrict__ hist,
                                                 const int* __restrict__ boff,
                                                 unsigned* __restrict__ part,
                                                 int E_, int nbins, int nblk){
    __shared__ int cur[1024];
    int t = threadIdx.x, blk = blockIdx.x;
    for (int i = t; i < nbins; i += 256)
        cur[i] = boff[i] + hist[(size_t)i * nblk + blk];
    __syncthreads();
    int base = blk * 8192;
    #pragma unroll 4
    for (int j = 0; j < 32; j++){
        int e = base + j * 256 + t;
        if (e < E_){
            int d = dst[e];
            unsigned s = (unsigned)src[e];
            int p = atomicAdd(&cur[d >> 7], 1);   // LDS atomic
            part[p] = ((unsigned)(d & 127) << 25) | s;
        }
    }
}

// one block per bin: local count/scan/rank in LDS; coalesced csr write.
// Also emits cnt[node] and off[node] for the bin's 128 nodes.
__global__ __launch_bounds__(256) void k_binsort(const unsigned* __restrict__ part,
                                                 const int* __restrict__ boff,
                                                 int* __restrict__ csr,
                                                 int* __restrict__ cnt,
                                                 int* __restrict__ off,
                                                 int n, int nbins){
    int b = blockIdx.x, t = threadIdx.x;
    int s0 = boff[b], s1 = boff[b + 1], len = s1 - s0;
    __shared__ int cl[128], sc[128], cur[128];
    __shared__ unsigned buf[4096], outb[4096];
    if (t < 128){ cl[t] = 0; cur[t] = 0; }
    __syncthreads();
    if (len <= 4096){
        for (int i = t; i < len; i += 256) buf[i] = part[s0 + i];
        __syncthreads();
        for (int i = t; i < len; i += 256) atomicAdd(&cl[buf[i] >> 25], 1);
        __syncthreads();
        if (t < 128) sc[t] = cl[t];
        __syncthreads();
        for (int o = 1; o < 128; o <<= 1){
            int v = 0;
            if (t < 128 && t >= o) v = sc[t - o];
            __syncthreads();
            if (t < 128) sc[t] += v;
            __syncthreads();
        }
        for (int i = t; i < len; i += 256){
            unsigned w = buf[i];
            int nd = (int)(w >> 25);
            int p = (sc[nd] - cl[nd]) + atomicAdd(&cur[nd], 1);
            outb[p] = w & 0x1FFFFFFu;
        }
        __syncthreads();
        for (int i = t; i < len; i += 256) csr[s0 + i] = (int)outb[i];
    } else {
        // fallback (never expected at these sizes): two global passes
        for (int i = t; i < len; i += 256) atomicAdd(&cl[part[s0 + i] >> 25], 1);
        __syncthreads();
        if (t < 128) sc[t] = cl[t];
        __syncthreads();
        for (int o = 1; o < 128; o <<= 1){
            int v = 0;
            if (t < 128 && t >= o) v = sc[t - o];
            __syncthreads();
            if (t < 128) sc[t] += v;
            __syncthreads();
        }
        for (int i = t; i < len; i += 256){
            unsigned w = part[s0 + i];
            int nd = (int)(w >> 25);
            int p = (sc[nd] - cl[nd]) + atomicAdd(&cur[nd], 1);
            csr[s0 + p] = (int)(w & 0x1FFFFFFu);
        }
    }
    if (t < 128){
        int node = b * 128 + t;
        if (node < n){
            cnt[node] = cl[t];
            off[node] = s0 + (sc[t] - cl[t]);
        }
    }
}

__global__ __launch_bounds__(256) void k_dinv(const int* __restrict__ cnt,
                                              float* __restrict__ dinv, int n){
    int i = blockIdx.x * 256 + threadIdx.x;
    if (i < n) dinv[i] = rsqrtf((float)cnt[i] + 1.0f);
}

// ---------------- weight reorder to MFMA B-fragment order ----------------
__global__ __launch_bounds__(256) void k_wconv(const float* __restrict__ W1,
                                               const float* __restrict__ W2,
                                               unsigned short* __restrict__ wf1,
                                               unsigned short* __restrict__ wf2){
    int f = blockIdx.x * 256 + threadIdx.x;
    if (f >= 3072) return;
    const float* W; unsigned short* o; int ncol, lf;
    if (f < 2048){ W = W1; o = wf1; ncol = 128; lf = f; }
    else         { W = W2; o = wf2; ncol = 64;  lf = f - 2048; }
    int lane = lf & 63;
    int ctkc = lf >> 6;
    int kc = ctkc & 3, ct = ctkc >> 2;
    int col = ct * 16 + (lane & 15);
    int k0  = kc * 32 + (lane >> 4) * 8;
    unsigned short* d = o + (size_t)lf * 8;
    #pragma unroll
    for (int j = 0; j < 8; j++) d[j] = f2b(W[(k0 + j) * ncol + col]);
}

// ---------------- GEMM1: hs1 = bf16( (x @ W1) * dinv[row] ) ----------------
__global__ __launch_bounds__(256) void k_gemm1(const float* __restrict__ x,
                                               const unsigned short* __restrict__ wf,
                                               const float* __restrict__ dinv,
                                               unsigned short* __restrict__ hs, int n){
    __shared__ unsigned short Wl[16384];
    __shared__ unsigned short Al[64 * 136];
    int t = threadIdx.x;
    long rowBase = (long)blockIdx.x * 64;
    {
        const uint4* s4 = (const uint4*)wf;
        uint4* d4 = (uint4*)Wl;
        #pragma unroll
        for (int i = 0; i < 8; i++) d4[t + i * 256] = s4[t + i * 256];
    }
    {
        const float4* xs = (const float4*)(x + rowBase * 128);
        #pragma unroll
        for (int k = 0; k < 8; k++){
            int i = t + k * 256;
            int r = i >> 5, c4 = (i & 31) << 2;
            float4 v = make_float4(0.f, 0.f, 0.f, 0.f);
            if (rowBase + r < n) v = xs[i];
            unsigned lo = (unsigned)f2b(v.x) | ((unsigned)f2b(v.y) << 16);
            unsigned hi = (unsigned)f2b(v.z) | ((unsigned)f2b(v.w) << 16);
            *(uint2*)&Al[r * 136 + c4] = make_uint2(lo, hi);
        }
    }
    __syncthreads();
    int w = t >> 6, lane = t & 63, lr = lane & 15, q = lane >> 4;
    floatx4 zero = {0.f, 0.f, 0.f, 0.f};
    floatx4 acc[8];
    #pragma unroll
    for (int ct = 0; ct < 8; ct++) acc[ct] = zero;
    #pragma unroll
    for (int kc = 0; kc < 4; kc++){
        bf16x8 af = *(const bf16x8*)&Al[(w * 16 + lr) * 136 + kc * 32 + q * 8];
        #pragma unroll
        for (int ct = 0; ct < 8; ct++){
            bf16x8 bf = *(const bf16x8*)&Wl[((ct * 4 + kc) * 64 + lane) * 8];
            acc[ct] = __builtin_amdgcn_mfma_f32_16x16x32_bf16(af, bf, acc[ct], 0, 0, 0);
        }
    }
    long r0 = rowBase + w * 16 + q * 4;
    #pragma unroll
    for (int r = 0; r < 4; r++){
        long row = r0 + r;
        if (row >= n) continue;
        float dv = dinv[row];
        unsigned short* orow = hs + row * 128 + lr;
        #pragma unroll
        for (int ct = 0; ct < 8; ct++) orow[ct * 16] = f2b(acc[ct][r] * dv);
    }
}

// ---------------- GEMM2: hs2 = bf16( (z1 @ W2) * dinv[row] ) ----------------
__global__ __launch_bounds__(256) void k_gemm2(const unsigned short* __restrict__ z1,
                                               const unsigned short* __restrict__ wf,
                                               const float* __restrict__ dinv,
                                               unsigned short* __restrict__ hs, int n){
    __shared__ unsigned short Wl[8192];
    __shared__ unsigned short Al[64 * 136];
    int t = threadIdx.x;
    long rowBase = (long)blockIdx.x * 64;
    {
        const uint4* s4 = (const uint4*)wf;
        uint4* d4 = (uint4*)Wl;
        #pragma unroll
        for (int i = 0; i < 4; i++) d4[t + i * 256] = s4[t + i * 256];
    }
    {
        const uint4* zs = (const uint4*)(z1 + rowBase * 128);
        #pragma unroll
        for (int k = 0; k < 4; k++){
            int i = t + k * 256;
            int r = i >> 4, c8 = (i & 15) << 3;
            uint4 v = make_uint4(0u, 0u, 0u, 0u);
            if (rowBase + r < n) v = zs[i];
            *(uint4*)&Al[r * 136 + c8] = v;
        }
    }
    __syncthreads();
    int w = t >> 6, lane = t & 63, lr = lane & 15, q = lane >> 4;
    floatx4 zero = {0.f, 0.f, 0.f, 0.f};
    floatx4 acc[4];
    #pragma unroll
    for (int ct = 0; ct < 4; ct++) acc[ct] = zero;
    #pragma unroll
    for (int kc = 0; kc < 4; kc++){
        bf16x8 af = *(const bf16x8*)&Al[(w * 16 + lr) * 136 + kc * 32 + q * 8];
        #pragma unroll
        for (int ct = 0; ct < 4; ct++){
            bf16x8 bf = *(const bf16x8*)&Wl[((ct * 4 + kc) * 64 + lane) * 8];
            acc[ct] = __builtin_amdgcn_mfma_f32_16x16x32_bf16(af, bf, acc[ct], 0, 0, 0);
        }
    }
    long r0 = rowBase + w * 16 + q * 4;
    #pragma unroll
    for (int r = 0; r < 4; r++){
        long row = r0 + r;
        if (row >= n) continue;
        float dv = dinv[row];
        unsigned short* orow = hs + row * 64 + lr;
        #pragma unroll
        for (int ct = 0; ct < 4; ct++) orow[ct * 16] = f2b(acc[ct][r] * dv);
    }
}

// ---------------- aggregation layer 1 (128 cols, wave per node) ----------------
__global__ __launch_bounds__(256) void k_agg1(const unsigned short* __restrict__ hs,
                                              const int* __restrict__ off,
                                              const int* __restrict__ cnt,
                                              const int* __restrict__ csr,
                                              const float* __restrict__ dinv,
                                              const float* __restrict__ b,
                                              unsigned short* __restrict__ z, int n){
    int wid = (blockIdx.x * 256 + threadIdx.x) >> 6;
    int lane = threadIdx.x & 63;
    if (wid >= n) return;
    size_t i = (size_t)wid;
    int start = off[wid], c = cnt[wid];
    unsigned v0 = *(const unsigned*)(hs + i * 128 + lane * 2);
    float a0 = b2f((unsigned short)v0);
    float a1 = b2f((unsigned short)(v0 >> 16));
    for (int base = 0; base < c; base += 64){
        int m = c - base; if (m > 64) m = 64;
        int sl = (base + lane < c) ? csr[start + base + lane] : 0;
        for (int j = 0; j < m; j++){
            size_t s = (size_t)__shfl(sl, j);
            unsigned v = *(const unsigned*)(hs + s * 128 + lane * 2);
            a0 += b2f((unsigned short)v);
            a1 += b2f((unsigned short)(v >> 16));
        }
    }
    float dv = dinv[wid];
    float2 bb = ((const float2*)b)[lane];
    float z0 = fmaxf(fmaf(dv, a0, bb.x), 0.f);
    float z1 = fmaxf(fmaf(dv, a1, bb.y), 0.f);
    *(unsigned*)(z + i * 128 + lane * 2) = (unsigned)f2b(z0) | ((unsigned)f2b(z1) << 16);
}

// ---------------- aggregation layer 2 (64 cols, wave per node, fp32 out) -------
__global__ __launch_bounds__(256) void k_agg2(const unsigned short* __restrict__ hs,
                                              const int* __restrict__ off,
                                              const int* __restrict__ cnt,
                                              const int* __restrict__ csr,
                                              const float* __restrict__ dinv,
                                              const float* __restrict__ b,
                                              float* __restrict__ z, int n){
    int wid = (blockIdx.x * 256 + threadIdx.x) >> 6;
    int lane = threadIdx.x & 63;
    if (wid >= n) return;
    size_t i = (size_t)wid;
    int start = off[wid], c = cnt[wid];
    float a = b2f(hs[i * 64 + lane]);
    for (int base = 0; base < c; base += 64){
        int m = c - base; if (m > 64) m = 64;
        int sl = (base + lane < c) ? csr[start + base + lane] : 0;
        for (int j = 0; j < m; j++){
            size_t s = (size_t)__shfl(sl, j);
            a += b2f(hs[s * 64 + lane]);
        }
    }
    z[i * 64 + lane] = fmaf(dinv[wid], a, b[lane]);
}

// ---------------- decode: out[e] = dot(z2[s], z2[t]) over 64 dims --------------
__global__ __launch_bounds__(256) void k_decode(const float* __restrict__ z,
                                                const int* __restrict__ es,
                                                const int* __restrict__ et,
                                                float* __restrict__ out, int m){
    int wid = (blockIdx.x * 256 + threadIdx.x) >> 6;
    int lane = threadIdx.x & 63;
    if (wid >= m) return;
    size_t s = (size_t)es[wid], t2 = (size_t)et[wid];
    float p = z[s * 64 + lane] * z[t2 * 64 + lane];
    #pragma unroll
    for (int o = 32; o > 0; o >>= 1) p += __shfl_xor(p, o);
    if (lane == 0) out[wid] = p;
}

// ---------------- launcher ----------------

extern "C" void kernel_launch(void* const* d_in, const int* in_sizes, int n_in,
                              void* d_out, int out_size, void* d_ws, size_t ws_size,
                              hipStream_t stream){
    const float* x   = (const float*)d_in[0];
    const int*   ei  = (const int*)d_in[1];
    const int*   eli = (const int*)d_in[2];
    const float* W1  = (const float*)d_in[3];
    const float* b1  = (const float*)d_in[4];
    const float* W2  = (const float*)d_in[5];
    const float* b2  = (const float*)d_in[6];
    float* out = (float*)d_out;

    int N_  = in_sizes[0] / 128;
    int E_  = in_sizes[1] / 2;
    int EL_ = in_sizes[2] / 2;
    int NBINS = (N_ + 127) >> 7;           // 782 for N=100k (must be <= 1024)
    const int EPB = 8192;
    int NBLK = (E_ + EPB - 1) / EPB;       // 196 for E=1.6M

    char* w = (char*)d_ws;
    size_t o = 0;
    auto alloc = [&](size_t bytes) -> size_t {
        size_t r = o; o += (bytes + 511) & ~(size_t)511; return r;
    };
    size_t o_cnt  = alloc((size_t)N_ * 4);
    size_t o_off  = alloc((size_t)N_ * 4);
    size_t o_dinv = alloc((size_t)N_ * 4);
    size_t o_btot = alloc((size_t)NBINS * 4);
    size_t o_boff = alloc((size_t)(NBINS + 1) * 4);
    size_t o_csr  = alloc((size_t)E_ * 4);
    size_t o_wf1  = alloc(16384 * 2);
    size_t o_wf2  = alloc(8192 * 2);
    size_t o_hs1  = alloc((size_t)N_ * 128 * 2);
    size_t o_z1   = alloc((size_t)N_ * 128 * 2);

    int* cnt  = (int*)(w + o_cnt);
    int* off  = (int*)(w + o_off);
    float* dinv = (float*)(w + o_dinv);
    int* btot = (int*)(w + o_btot);
    int* boff = (int*)(w + o_boff);
    int* csr  = (int*)(w + o_csr);
    unsigned short* wf1 = (unsigned short*)(w + o_wf1);
    unsigned short* wf2 = (unsigned short*)(w + o_wf2);
    unsigned short* hs1 = (unsigned short*)(w + o_hs1);
    unsigned short* z1  = (unsigned short*)(w + o_z1);
    unsigned short* hs2 = hs1;                 // hs1 dead after agg1
    float* z2 = (float*)(w + o_z1);            // z1 dead after gemm2

    // hist and part alias the hs1 region (dead before k_gemm1 writes hs1)
    int* hist = (int*)(w + o_hs1);                         // NBINS*NBLK*4 ≈ 613KB
    unsigned* part = (unsigned*)(w + o_hs1 + 4u * 1024u * 1024u);   // E*4 = 6.4MB

    k_hist    <<<NBLK, 256, 0, stream>>>(ei + E_, hist, E_, NBINS, NBLK);
    k_binscanA<<<NBINS, 64, 0, stream>>>(hist, btot, NBLK);
    k_binscanB<<<1, 1024, 0, stream>>>(btot, boff, NBINS);
    k_scatter <<<NBLK, 256, 0, stream>>>(ei, ei + E_, hist, boff, part, E_, NBINS, NBLK);
    k_binsort <<<NBINS, 256, 0, stream>>>(part, boff, csr, cnt, off, N_, NBINS);
    k_dinv    <<<(N_ + 255) / 256, 256, 0, stream>>>(cnt, dinv, N_);
    k_wconv   <<<12, 256, 0, stream>>>(W1, W2, wf1, wf2);
    k_gemm1   <<<(N_ + 63) / 64, 256, 0, stream>>>(x, wf1, dinv, hs1, N_);
    k_agg1    <<<(N_ + 3) / 4, 256, 0, stream>>>(hs1, off, cnt, csr, dinv, b1, z1, N_);
    k_gemm2   <<<(N_ + 63) / 64, 256, 0, stream>>>(z1, wf2, dinv, hs2, N_);
    k_agg2    <<<(N_ + 3) / 4, 256, 0, stream>>>(hs2, off, cnt, csr, dinv, b2, z2, N_);
    k_decode  <<<(EL_ + 3) / 4, 256, 0, stream>>>(z2, eli, eli + EL_, out, EL_);
}

// Round 5
// 317.389 us; speedup vs baseline: 1.7348x; 1.3102x over previous
//
#include <hip/hip_runtime.h>
#include <stdint.h>

typedef __bf16 bf16x8 __attribute__((ext_vector_type(8)));
typedef float  floatx4 __attribute__((ext_vector_type(4)));

__device__ __forceinline__ unsigned short f2b(float x){
    unsigned u = __float_as_uint(x);
    u = u + 0x7FFFu + ((u >> 16) & 1u);          // RNE
    return (unsigned short)(u >> 16);
}
__device__ __forceinline__ float b2f(unsigned short h){
    return __uint_as_float(((unsigned)h) << 16);
}

// ================= CSR build: two-level counting sort (no global atomics) ====
// bin = dst >> 7 (128 nodes per bin). EPB = 8192 edges per hist/scatter block.

__global__ __launch_bounds__(256) void k_hist(const int* __restrict__ dst,
                                              int* __restrict__ hist,
                                              int E_, int nbins, int nblk){
    __shared__ int h[1024];
    int t = threadIdx.x, blk = blockIdx.x;
    for (int i = t; i < nbins; i += 256) h[i] = 0;
    __syncthreads();
    int base = blk * 8192;
    #pragma unroll
    for (int j = 0; j < 8; j++){
        int e = base + (j * 256 + t) * 4;
        if (e < E_){
            int4 d = *(const int4*)(dst + e);
            atomicAdd(&h[d.x >> 7], 1);
            atomicAdd(&h[d.y >> 7], 1);
            atomicAdd(&h[d.z >> 7], 1);
            atomicAdd(&h[d.w >> 7], 1);
        }
    }
    __syncthreads();
    for (int i = t; i < nbins; i += 256) hist[(size_t)i * nblk + blk] = h[i];
}

// per-bin exclusive scan across blocks, in place; bin totals out. 1 wave/bin.
__global__ __launch_bounds__(64) void k_binscanA(int* __restrict__ hist,
                                                 int* __restrict__ btot, int nblk){
    int bin = blockIdx.x, lane = threadIdx.x;
    int carry = 0;
    for (int base = 0; base < nblk; base += 64){
        int idx = bin * nblk + base + lane;
        bool inb = (base + lane) < nblk;
        int v = inb ? hist[idx] : 0;
        int orig = v;
        #pragma unroll
        for (int o = 1; o < 64; o <<= 1){
            int u = __shfl_up(v, o);
            if (lane >= o) v += u;
        }
        if (inb) hist[idx] = v - orig + carry;
        carry += __shfl(v, 63);
    }
    if (lane == 0) btot[bin] = carry;
}

// scan of bin totals -> binoff[0..nbins]  (requires nbins <= 1024)
__global__ __launch_bounds__(1024) void k_binscanB(const int* __restrict__ btot,
                                                   int* __restrict__ boff, int nbins){
    __shared__ int s[1024];
    int t = threadIdx.x;
    s[t] = (t < nbins) ? btot[t] : 0;
    __syncthreads();
    for (int o = 1; o < 1024; o <<= 1){
        int v = (t >= o) ? s[t - o] : 0;
        __syncthreads();
        s[t] += v;
        __syncthreads();
    }
    if (t == 0) boff[0] = 0;
    if (t < nbins) boff[t + 1] = s[t];
}

// partition edges into bin segments; positions via LDS counters only.
// packed word (UNSIGNED): (dst & 127) << 25 | src     (needs N < 2^25)
__global__ __launch_bounds__(256) void k_scatter(const int* __restrict__ src,
                                                 const int* __restrict__ dst,
                                                 const int* __restrict__ hist,
                                                 const int* __restrict__ boff,
                                                 unsigned* __restrict__ part,
                                                 int E_, int nbins, int nblk){
    __shared__ int cur[1024];
    int t = threadIdx.x, blk = blockIdx.x;
    for (int i = t; i < nbins; i += 256)
        cur[i] = boff[i] + hist[(size_t)i * nblk + blk];
    __syncthreads();
    int base = blk * 8192;
    #pragma unroll
    for (int j = 0; j < 8; j++){
        int e = base + (j * 256 + t) * 4;
        if (e < E_){
            int4 d = *(const int4*)(dst + e);
            int4 s = *(const int4*)(src + e);
            int p0 = atomicAdd(&cur[d.x >> 7], 1);
            part[p0] = ((unsigned)(d.x & 127) << 25) | (unsigned)s.x;
            int p1 = atomicAdd(&cur[d.y >> 7], 1);
            part[p1] = ((unsigned)(d.y & 127) << 25) | (unsigned)s.y;
            int p2 = atomicAdd(&cur[d.z >> 7], 1);
            part[p2] = ((unsigned)(d.z & 127) << 25) | (unsigned)s.z;
            int p3 = atomicAdd(&cur[d.w >> 7], 1);
            part[p3] = ((unsigned)(d.w & 127) << 25) | (unsigned)s.w;
        }
    }
}

// one block per bin: local count/scan/rank in LDS; coalesced csr write.
// Also emits cnt[node], off[node], dinv[node] for the bin's 128 nodes.
__global__ __launch_bounds__(256) void k_binsort(const unsigned* __restrict__ part,
                                                 const int* __restrict__ boff,
                                                 int* __restrict__ csr,
                                                 int* __restrict__ cnt,
                                                 int* __restrict__ off,
                                                 float* __restrict__ dinv,
                                                 int n, int nbins){
    int b = blockIdx.x, t = threadIdx.x;
    int s0 = boff[b], s1 = boff[b + 1], len = s1 - s0;
    __shared__ int cl[128], sc[128], cur[128];
    __shared__ unsigned buf[4096], outb[4096];
    if (t < 128){ cl[t] = 0; cur[t] = 0; }
    __syncthreads();
    if (len <= 4096){
        for (int i = t; i < len; i += 256) buf[i] = part[s0 + i];
        __syncthreads();
        for (int i = t; i < len; i += 256) atomicAdd(&cl[buf[i] >> 25], 1);
        __syncthreads();
        if (t < 128) sc[t] = cl[t];
        __syncthreads();
        for (int o = 1; o < 128; o <<= 1){
            int v = 0;
            if (t < 128 && t >= o) v = sc[t - o];
            __syncthreads();
            if (t < 128) sc[t] += v;
            __syncthreads();
        }
        for (int i = t; i < len; i += 256){
            unsigned w = buf[i];
            int nd = (int)(w >> 25);
            int p = (sc[nd] - cl[nd]) + atomicAdd(&cur[nd], 1);
            outb[p] = w & 0x1FFFFFFu;
        }
        __syncthreads();
        for (int i = t; i < len; i += 256) csr[s0 + i] = (int)outb[i];
    } else {
        // fallback (never expected at these sizes): two global passes
        for (int i = t; i < len; i += 256) atomicAdd(&cl[part[s0 + i] >> 25], 1);
        __syncthreads();
        if (t < 128) sc[t] = cl[t];
        __syncthreads();
        for (int o = 1; o < 128; o <<= 1){
            int v = 0;
            if (t < 128 && t >= o) v = sc[t - o];
            __syncthreads();
            if (t < 128) sc[t] += v;
            __syncthreads();
        }
        for (int i = t; i < len; i += 256){
            unsigned w = part[s0 + i];
            int nd = (int)(w >> 25);
            int p = (sc[nd] - cl[nd]) + atomicAdd(&cur[nd], 1);
            csr[s0 + p] = (int)(w & 0x1FFFFFFu);
        }
    }
    if (t < 128){
        int node = b * 128 + t;
        if (node < n){
            cnt[node] = cl[t];
            off[node] = s0 + (sc[t] - cl[t]);
            dinv[node] = rsqrtf((float)cl[t] + 1.0f);
        }
    }
}

// ---------------- weight reorder to MFMA B-fragment order ----------------
__global__ __launch_bounds__(256) void k_wconv(const float* __restrict__ W1,
                                               const float* __restrict__ W2,
                                               unsigned short* __restrict__ wf1,
                                               unsigned short* __restrict__ wf2){
    int f = blockIdx.x * 256 + threadIdx.x;
    if (f >= 3072) return;
    const float* W; unsigned short* o; int ncol, lf;
    if (f < 2048){ W = W1; o = wf1; ncol = 128; lf = f; }
    else         { W = W2; o = wf2; ncol = 64;  lf = f - 2048; }
    int lane = lf & 63;
    int ctkc = lf >> 6;
    int kc = ctkc & 3, ct = ctkc >> 2;
    int col = ct * 16 + (lane & 15);
    int k0  = kc * 32 + (lane >> 4) * 8;
    unsigned short* d = o + (size_t)lf * 8;
    #pragma unroll
    for (int j = 0; j < 8; j++) d[j] = f2b(W[(k0 + j) * ncol + col]);
}

// ---------------- GEMM1: hs1 = bf16( (x @ W1) * dinv[row] ) ----------------
__global__ __launch_bounds__(256) void k_gemm1(const float* __restrict__ x,
                                               const unsigned short* __restrict__ wf,
                                               const float* __restrict__ dinv,
                                               unsigned short* __restrict__ hs, int n){
    __shared__ unsigned short Wl[16384];
    __shared__ unsigned short Al[64 * 136];
    int t = threadIdx.x;
    long rowBase = (long)blockIdx.x * 64;
    {
        const uint4* s4 = (const uint4*)wf;
        uint4* d4 = (uint4*)Wl;
        #pragma unroll
        for (int i = 0; i < 8; i++) d4[t + i * 256] = s4[t + i * 256];
    }
    {
        const float4* xs = (const float4*)(x + rowBase * 128);
        #pragma unroll
        for (int k = 0; k < 8; k++){
            int i = t + k * 256;
            int r = i >> 5, c4 = (i & 31) << 2;
            float4 v = make_float4(0.f, 0.f, 0.f, 0.f);
            if (rowBase + r < n) v = xs[i];
            unsigned lo = (unsigned)f2b(v.x) | ((unsigned)f2b(v.y) << 16);
            unsigned hi = (unsigned)f2b(v.z) | ((unsigned)f2b(v.w) << 16);
            *(uint2*)&Al[r * 136 + c4] = make_uint2(lo, hi);
        }
    }
    __syncthreads();
    int w = t >> 6, lane = t & 63, lr = lane & 15, q = lane >> 4;
    floatx4 zero = {0.f, 0.f, 0.f, 0.f};
    floatx4 acc[8];
    #pragma unroll
    for (int ct = 0; ct < 8; ct++) acc[ct] = zero;
    #pragma unroll
    for (int kc = 0; kc < 4; kc++){
        bf16x8 af = *(const bf16x8*)&Al[(w * 16 + lr) * 136 + kc * 32 + q * 8];
        #pragma unroll
        for (int ct = 0; ct < 8; ct++){
            bf16x8 bf = *(const bf16x8*)&Wl[((ct * 4 + kc) * 64 + lane) * 8];
            acc[ct] = __builtin_amdgcn_mfma_f32_16x16x32_bf16(af, bf, acc[ct], 0, 0, 0);
        }
    }
    long r0 = rowBase + w * 16 + q * 4;
    #pragma unroll
    for (int r = 0; r < 4; r++){
        long row = r0 + r;
        if (row >= n) continue;
        float dv = dinv[row];
        unsigned short* orow = hs + row * 128 + lr;
        #pragma unroll
        for (int ct = 0; ct < 8; ct++) orow[ct * 16] = f2b(acc[ct][r] * dv);
    }
}

// ---------------- GEMM2: hs2 = bf16( (z1 @ W2) * dinv[row] ) ----------------
__global__ __launch_bounds__(256) void k_gemm2(const unsigned short* __restrict__ z1,
                                               const unsigned short* __restrict__ wf,
                                               const float* __restrict__ dinv,
                                               unsigned short* __restrict__ hs, int n){
    __shared__ unsigned short Wl[8192];
    __shared__ unsigned short Al[64 * 136];
    int t = threadIdx.x;
    long rowBase = (long)blockIdx.x * 64;
    {
        const uint4* s4 = (const uint4*)wf;
        uint4* d4 = (uint4*)Wl;
        #pragma unroll
        for (int i = 0; i < 4; i++) d4[t + i * 256] = s4[t + i * 256];
    }
    {
        const uint4* zs = (const uint4*)(z1 + rowBase * 128);
        #pragma unroll
        for (int k = 0; k < 4; k++){
            int i = t + k * 256;
            int r = i >> 4, c8 = (i & 15) << 3;
            uint4 v = make_uint4(0u, 0u, 0u, 0u);
            if (rowBase + r < n) v = zs[i];
            *(uint4*)&Al[r * 136 + c8] = v;
        }
    }
    __syncthreads();
    int w = t >> 6, lane = t & 63, lr = lane & 15, q = lane >> 4;
    floatx4 zero = {0.f, 0.f, 0.f, 0.f};
    floatx4 acc[4];
    #pragma unroll
    for (int ct = 0; ct < 4; ct++) acc[ct] = zero;
    #pragma unroll
    for (int kc = 0; kc < 4; kc++){
        bf16x8 af = *(const bf16x8*)&Al[(w * 16 + lr) * 136 + kc * 32 + q * 8];
        #pragma unroll
        for (int ct = 0; ct < 4; ct++){
            bf16x8 bf = *(const bf16x8*)&Wl[((ct * 4 + kc) * 64 + lane) * 8];
            acc[ct] = __builtin_amdgcn_mfma_f32_16x16x32_bf16(af, bf, acc[ct], 0, 0, 0);
        }
    }
    long r0 = rowBase + w * 16 + q * 4;
    #pragma unroll
    for (int r = 0; r < 4; r++){
        long row = r0 + r;
        if (row >= n) continue;
        float dv = dinv[row];
        unsigned short* orow = hs + row * 64 + lr;
        #pragma unroll
        for (int ct = 0; ct < 4; ct++) orow[ct * 16] = f2b(acc[ct][r] * dv);
    }
}

// ---------------- aggregation layer 1 (128 cols, wave per node) ----------------
// Unrolled x8: 8 independent row loads in flight (latency-bound fix).
__global__ __launch_bounds__(256) void k_agg1(const unsigned short* __restrict__ hs,
                                              const int* __restrict__ off,
                                              const int* __restrict__ cnt,
                                              const int* __restrict__ csr,
                                              const float* __restrict__ dinv,
                                              const float* __restrict__ b,
                                              unsigned short* __restrict__ z, int n){
    int wid = (blockIdx.x * 256 + threadIdx.x) >> 6;
    int lane = threadIdx.x & 63;
    if (wid >= n) return;
    size_t i = (size_t)wid;
    int start = off[wid], c = cnt[wid];
    unsigned v0 = *(const unsigned*)(hs + i * 128 + lane * 2);
    float a0 = b2f((unsigned short)v0);
    float a1 = b2f((unsigned short)(v0 >> 16));
    int j = 0;
    for (; j + 8 <= c; j += 8){
        size_t s0 = (size_t)csr[start + j + 0];
        size_t s1 = (size_t)csr[start + j + 1];
        size_t s2 = (size_t)csr[start + j + 2];
        size_t s3 = (size_t)csr[start + j + 3];
        size_t s4 = (size_t)csr[start + j + 4];
        size_t s5 = (size_t)csr[start + j + 5];
        size_t s6 = (size_t)csr[start + j + 6];
        size_t s7 = (size_t)csr[start + j + 7];
        unsigned w0 = *(const unsigned*)(hs + s0 * 128 + lane * 2);
        unsigned w1 = *(const unsigned*)(hs + s1 * 128 + lane * 2);
        unsigned w2 = *(const unsigned*)(hs + s2 * 128 + lane * 2);
        unsigned w3 = *(const unsigned*)(hs + s3 * 128 + lane * 2);
        unsigned w4 = *(const unsigned*)(hs + s4 * 128 + lane * 2);
        unsigned w5 = *(const unsigned*)(hs + s5 * 128 + lane * 2);
        unsigned w6 = *(const unsigned*)(hs + s6 * 128 + lane * 2);
        unsigned w7 = *(const unsigned*)(hs + s7 * 128 + lane * 2);
        a0 += b2f((unsigned short)w0); a1 += b2f((unsigned short)(w0 >> 16));
        a0 += b2f((unsigned short)w1); a1 += b2f((unsigned short)(w1 >> 16));
        a0 += b2f((unsigned short)w2); a1 += b2f((unsigned short)(w2 >> 16));
        a0 += b2f((unsigned short)w3); a1 += b2f((unsigned short)(w3 >> 16));
        a0 += b2f((unsigned short)w4); a1 += b2f((unsigned short)(w4 >> 16));
        a0 += b2f((unsigned short)w5); a1 += b2f((unsigned short)(w5 >> 16));
        a0 += b2f((unsigned short)w6); a1 += b2f((unsigned short)(w6 >> 16));
        a0 += b2f((unsigned short)w7); a1 += b2f((unsigned short)(w7 >> 16));
    }
    for (; j < c; j++){
        size_t s = (size_t)csr[start + j];
        unsigned v = *(const unsigned*)(hs + s * 128 + lane * 2);
        a0 += b2f((unsigned short)v);
        a1 += b2f((unsigned short)(v >> 16));
    }
    float dv = dinv[wid];
    float2 bb = ((const float2*)b)[lane];
    float z0 = fmaxf(fmaf(dv, a0, bb.x), 0.f);
    float z1 = fmaxf(fmaf(dv, a1, bb.y), 0.f);
    *(unsigned*)(z + i * 128 + lane * 2) = (unsigned)f2b(z0) | ((unsigned)f2b(z1) << 16);
}

// ---------------- aggregation layer 2 (64 cols, wave per node, fp32 out) -------
__global__ __launch_bounds__(256) void k_agg2(const unsigned short* __restrict__ hs,
                                              const int* __restrict__ off,
                                              const int* __restrict__ cnt,
                                              const int* __restrict__ csr,
                                              const float* __restrict__ dinv,
                                              const float* __restrict__ b,
                                              float* __restrict__ z, int n){
    int wid = (blockIdx.x * 256 + threadIdx.x) >> 6;
    int lane = threadIdx.x & 63;
    if (wid >= n) return;
    size_t i = (size_t)wid;
    int start = off[wid], c = cnt[wid];
    float a = b2f(hs[i * 64 + lane]);
    int j = 0;
    for (; j + 8 <= c; j += 8){
        size_t s0 = (size_t)csr[start + j + 0];
        size_t s1 = (size_t)csr[start + j + 1];
        size_t s2 = (size_t)csr[start + j + 2];
        size_t s3 = (size_t)csr[start + j + 3];
        size_t s4 = (size_t)csr[start + j + 4];
        size_t s5 = (size_t)csr[start + j + 5];
        size_t s6 = (size_t)csr[start + j + 6];
        size_t s7 = (size_t)csr[start + j + 7];
        unsigned short h0 = hs[s0 * 64 + lane];
        unsigned short h1 = hs[s1 * 64 + lane];
        unsigned short h2 = hs[s2 * 64 + lane];
        unsigned short h3 = hs[s3 * 64 + lane];
        unsigned short h4 = hs[s4 * 64 + lane];
        unsigned short h5 = hs[s5 * 64 + lane];
        unsigned short h6 = hs[s6 * 64 + lane];
        unsigned short h7 = hs[s7 * 64 + lane];
        a += b2f(h0); a += b2f(h1); a += b2f(h2); a += b2f(h3);
        a += b2f(h4); a += b2f(h5); a += b2f(h6); a += b2f(h7);
    }
    for (; j < c; j++){
        size_t s = (size_t)csr[start + j];
        a += b2f(hs[s * 64 + lane]);
    }
    z[i * 64 + lane] = fmaf(dinv[wid], a, b[lane]);
}

// ---------------- decode: out[e] = dot(z2[s], z2[t]); 2 edges per wave ---------
// Grid: one 256-thread block covers 4 waves x 2 = 8 edges.
__global__ __launch_bounds__(256) void k_decode(const float* __restrict__ z,
                                                const int* __restrict__ es,
                                                const int* __restrict__ et,
                                                float* __restrict__ out, int m){
    int wv = (blockIdx.x * 256 + threadIdx.x) >> 6;
    int lane = threadIdx.x & 63;
    int e = wv * 2 + (lane >> 5);
    int hl = lane & 31;
    float p = 0.f;
    if (e < m){
        size_t s = (size_t)es[e], t2 = (size_t)et[e];
        float2 xs = *(const float2*)(z + s * 64 + hl * 2);
        float2 xt = *(const float2*)(z + t2 * 64 + hl * 2);
        p = xs.x * xt.x + xs.y * xt.y;
    }
    #pragma unroll
    for (int o = 16; o > 0; o >>= 1) p += __shfl_xor(p, o);
    if (hl == 0 && e < m) out[e] = p;
}

// ---------------- launcher ----------------

extern "C" void kernel_launch(void* const* d_in, const int* in_sizes, int n_in,
                              void* d_out, int out_size, void* d_ws, size_t ws_size,
                              hipStream_t stream){
    const float* x   = (const float*)d_in[0];
    const int*   ei  = (const int*)d_in[1];
    const int*   eli = (const int*)d_in[2];
    const float* W1  = (const float*)d_in[3];
    const float* b1  = (const float*)d_in[4];
    const float* W2  = (const float*)d_in[5];
    const float* b2  = (const float*)d_in[6];
    float* out = (float*)d_out;

    int N_  = in_sizes[0] / 128;
    int E_  = in_sizes[1] / 2;
    int EL_ = in_sizes[2] / 2;
    int NBINS = (N_ + 127) >> 7;           // 782 for N=100k (must be <= 1024)
    const int EPB = 8192;
    int NBLK = (E_ + EPB - 1) / EPB;       // 196 for E=1.6M

    char* w = (char*)d_ws;
    size_t o = 0;
    auto alloc = [&](size_t bytes) -> size_t {
        size_t r = o; o += (bytes + 511) & ~(size_t)511; return r;
    };
    size_t o_cnt  = alloc((size_t)N_ * 4);
    size_t o_off  = alloc((size_t)N_ * 4);
    size_t o_dinv = alloc((size_t)N_ * 4);
    size_t o_btot = alloc((size_t)NBINS * 4);
    size_t o_boff = alloc((size_t)(NBINS + 1) * 4);
    size_t o_csr  = alloc((size_t)E_ * 4);
    size_t o_wf1  = alloc(16384 * 2);
    size_t o_wf2  = alloc(8192 * 2);
    size_t o_hs1  = alloc((size_t)N_ * 128 * 2);
    size_t o_z1   = alloc((size_t)N_ * 128 * 2);

    int* cnt  = (int*)(w + o_cnt);
    int* off  = (int*)(w + o_off);
    float* dinv = (float*)(w + o_dinv);
    int* btot = (int*)(w + o_btot);
    int* boff = (int*)(w + o_boff);
    int* csr  = (int*)(w + o_csr);
    unsigned short* wf1 = (unsigned short*)(w + o_wf1);
    unsigned short* wf2 = (unsigned short*)(w + o_wf2);
    unsigned short* hs1 = (unsigned short*)(w + o_hs1);
    unsigned short* z1  = (unsigned short*)(w + o_z1);
    unsigned short* hs2 = hs1;                 // hs1 dead after agg1
    float* z2 = (float*)(w + o_z1);            // z1 dead after gemm2

    // hist and part alias the hs1 region (dead before k_gemm1 writes hs1)
    int* hist = (int*)(w + o_hs1);                         // NBINS*NBLK*4 ≈ 613KB
    unsigned* part = (unsigned*)(w + o_hs1 + 4u * 1024u * 1024u);   // E*4 = 6.4MB

    k_hist    <<<NBLK, 256, 0, stream>>>(ei + E_, hist, E_, NBINS, NBLK);
    k_binscanA<<<NBINS, 64, 0, stream>>>(hist, btot, NBLK);
    k_binscanB<<<1, 1024, 0, stream>>>(btot, boff, NBINS);
    k_scatter <<<NBLK, 256, 0, stream>>>(ei, ei + E_, hist, boff, part, E_, NBINS, NBLK);
    k_binsort <<<NBINS, 256, 0, stream>>>(part, boff, csr, cnt, off, dinv, N_, NBINS);
    k_wconv   <<<12, 256, 0, stream>>>(W1, W2, wf1, wf2);
    k_gemm1   <<<(N_ + 63) / 64, 256, 0, stream>>>(x, wf1, dinv, hs1, N_);
    k_agg1    <<<(N_ + 3) / 4, 256, 0, stream>>>(hs1, off, cnt, csr, dinv, b1, z1, N_);
    k_gemm2   <<<(N_ + 63) / 64, 256, 0, stream>>>(z1, wf2, dinv, hs2, N_);
    k_agg2    <<<(N_ + 3) / 4, 256, 0, stream>>>(hs2, off, cnt, csr, dinv, b2, z2, N_);
    k_decode  <<<(EL_ + 7) / 8, 256, 0, stream>>>(z2, eli, eli + EL_, out, EL_);
}